// Round 3
// baseline (1333.832 us; speedup 1.0000x reference)
//
#include <hip/hip_runtime.h>
#include <math.h>

// ---------------- problem constants ----------------
#define NLAY 120         // LSTM layers
#define TT   1016        // LSTM time steps (1024 - 4 - 4)
#define NB   64          // batches of 16 steps (64*16 = 1024 >= TT+4)
#define RB   8           // L3 ring depth in batches (power of 2)
#define IRS  32          // intra-block inter-wave LDS ring slots (power of 2)
#define TPB  384         // 6 waves x 64 lanes; wave = 5 layers x 12 hidden (lanes 60-63 idle)
#define BIGF (1 << 20)

typedef float v2f __attribute__((ext_vector_type(2)));

__device__ __forceinline__ float fast_rcp(float x) { return __builtin_amdgcn_rcpf(x); }
__device__ __forceinline__ float fast_sig(float x) { return fast_rcp(1.f + __expf(-x)); }
__device__ __forceinline__ float fast_tanh(float x) { return 1.f - 2.f * fast_rcp(1.f + __expf(2.f * x)); }

// agent-scope relaxed poll (global flags); s_sleep on miss; watchdog fails loud, never hangs
__device__ __forceinline__ int poll_ge_ag(const int* p, int tgt, int cur) {
  long g = 0;
  while (cur < tgt) {
    cur = __hip_atomic_load(p, __ATOMIC_RELAXED, __HIP_MEMORY_SCOPE_AGENT);
    if (cur >= tgt) break;
    __builtin_amdgcn_s_sleep(1);
    if (++g > 400000L) break;
  }
  return cur;
}
// workgroup-scope relaxed poll on an LDS flag (ds_read spin)
__device__ __forceinline__ int poll_ge_wg(const int* p, int tgt, int cur) {
  long g = 0;
  while (cur < tgt) {
    cur = __hip_atomic_load(p, __ATOMIC_RELAXED, __HIP_MEMORY_SCOPE_WORKGROUP);
    if (cur >= tgt) break;
    __builtin_amdgcn_s_sleep(1);
    if (++g > 400000L) break;
  }
  return cur;
}

// ---------------- conv1d(6->6,K=5,valid) + bias, accumulate BN stats ----------------
__global__ void k_conv(const float* __restrict__ xin, const float* __restrict__ cw,
                       const float* __restrict__ cb, const float* __restrict__ aff,
                       float* __restrict__ yout, float* __restrict__ stat,
                       int Tin, int Tout, int use_aff)
{
  const int bx = blockIdx.x;            // 0..383 : b*6+co
  const int b = bx / 6, co = bx - b * 6;
  const int tid = threadIdx.x;          // 256
  __shared__ float wsh[30];
  __shared__ float ssh[6], shsh[6];
  if (tid < 30) wsh[tid] = cw[co * 30 + tid];
  if (tid < 6) {
    ssh[tid]  = use_aff ? aff[tid] : 1.f;
    shsh[tid] = use_aff ? aff[6 + tid] : 0.f;
  }
  __syncthreads();
  const float bias = cb[co];
  float lsum = 0.f, lsq = 0.f;
  for (int t = tid; t < Tout; t += 256) {
    float acc = bias;
#pragma unroll
    for (int ci = 0; ci < 6; ++ci) {
      const float* xr = xin + ((size_t)b * 6 + ci) * Tin + t;
      const float s = ssh[ci], sh = shsh[ci];
#pragma unroll
      for (int k = 0; k < 5; ++k) {
        float v = xr[k];
        if (use_aff) v = fmaxf(fmaf(s, v, sh), 0.f);
        acc += wsh[ci * 5 + k] * v;
      }
    }
    yout[((size_t)b * 6 + co) * Tout + t] = acc;
    lsum += acc; lsq += acc * acc;
  }
  __shared__ float rs[256], rq[256];
  rs[tid] = lsum; rq[tid] = lsq;
  __syncthreads();
  for (int s = 128; s > 0; s >>= 1) {
    if (tid < s) { rs[tid] += rs[tid + s]; rq[tid] += rq[tid + s]; }
    __syncthreads();
  }
  if (tid == 0) { atomicAdd(&stat[co], rs[0]); atomicAdd(&stat[6 + co], rq[0]); }
}

// ---------------- finalize BN: stats -> per-channel scale/shift ----------------
__global__ void k_finalize(const float* __restrict__ stat,
                           const float* __restrict__ gamma, const float* __restrict__ beta,
                           float* __restrict__ aff, float invN)
{
  const int c = threadIdx.x;
  if (c < 6) {
    float mean = stat[c] * invN;
    float var  = stat[6 + c] * invN - mean * mean;
    float sc   = gamma[c] * rsqrtf(var + 1e-5f);
    aff[c]     = sc;
    aff[6 + c] = fmaf(-mean, sc, beta[c]);
  }
}

// ---------------- BN2+ReLU + attn projection (6->12) + ReLU; write seq0[t][b*12+j] ----------------
__global__ void k_attn(const float* __restrict__ y2, const float* __restrict__ aff2,
                       const float* __restrict__ aw, const float* __restrict__ ab,
                       float* __restrict__ seq0)
{
  const int t = blockIdx.x;             // 0..1015
  const int tid = threadIdx.x;          // 0..767
  __shared__ float zb[6 * 64];
  if (tid < 384) {
    const int c = tid >> 6, bb = tid & 63;
    float v = y2[((size_t)bb * 6 + c) * TT + t];
    zb[c * 64 + bb] = fmaxf(fmaf(aff2[c], v, aff2[6 + c]), 0.f);
  }
  __syncthreads();
  const int b = tid / 12, j = tid - b * 12;
  float acc = ab[j];
#pragma unroll
  for (int c = 0; c < 6; ++c) acc += aw[j * 6 + c] * zb[c * 64 + b];
  seq0[(size_t)t * 768 + tid] = fmaxf(acc, 0.f);
}

// ---------------- 120-layer LSTM: free-running waves, TWO chains per lane ----------------
// grid = 128 blocks: bid = pair*4 + seg; pair handles chains cA=2*pair, cB=2*pair+1.
// Wave w = 5-layer stage; lane (p,j) = layer w*5+p, output j — for BOTH chains (weights are
// shared across batch, so the 96 weight VGPRs serve two independent recurrences).
// Rationale (r0-r2 evidence): period is latency-stall-bound (~75% stall/wave); chain B's
// FMAs+activations execute under chain A's LDS round-trip and vice versa. Blocks halve
// (128 CUs idle) — irrelevant when latency-bound. Datapath = round-0 exactly (best: 721us).
// Diagonal: at step s, group p computes t = s - p. Intra-wave hand-off: hloc double buffer.
// Wave->wave: iring + RELAXED LDS flags. Block->block: 16-step batches (384 floats: both
// chains) via L3 ring; only the tailer's prog post is RELEASE.
__global__ __launch_bounds__(TPB, 2) void k_lstm(
    const float* __restrict__ wih, const float* __restrict__ whh,
    const float* __restrict__ bih, const float* __restrict__ bhh,
    const float* __restrict__ seq0, float* __restrict__ ring,
    int* __restrict__ prog, int* __restrict__ cons,
    float* __restrict__ hfin)
{
  const int bid  = blockIdx.x;         // 0..127
  const int pr   = bid >> 2;           // pair = 0..31 (chains 2*pr, 2*pr+1)
  const int seg  = bid & 3;
  const int tid  = threadIdx.x;
  const int w    = tid >> 6;           // wave 0..5
  const int lane = tid & 63;
  const int p    = lane / 12;          // 0..5 (5 = pad group)
  const int j    = lane - p * 12;
  const bool act = (p < 5);
  const int pc   = act ? p : 0;        // clamped for safe addressing
  const int l    = seg * 30 + w * 5 + pc;

  // ---- LDS (chain dimension added) ----
  __shared__ __align__(16) float hloc[6][2][2][64];     // [wave][buf][chain][lane]
  __shared__ __align__(16) float iring[5][IRS][2][12];  // wave w -> w+1, per chain
  __shared__ __align__(16) float xring[2][16][2][12];   // feeder input [buf][t][chain][j]
  __shared__ __align__(16) float oring[16][2][12];      // tailer staging
  __shared__ int pflag[6];                              // produced-count, posted by wave w (w<5)
  __shared__ int cflag[8];                              // consumed-count, posted by wave w (w>0)
  float* xrf = &xring[0][0][0][0];

  if (tid < 6) pflag[tid] = 0;
  if (tid < 8) cflag[tid] = 0;
#pragma unroll
  for (int z = 0; z < 2; ++z) {
    hloc[w][0][z][lane] = 0.f; hloc[w][1][z][lane] = 0.f;
  }
  __syncthreads();   // ONE barrier, before the main loop only

  // ---- gate weights as (i,f),(g,o) float2 pairs -> v_pk_fma_f32 (shared by both chains) ----
  v2f wx_if[12], wx_go[12], wh_if[12], wh_go[12];
  v2f b_if = (v2f){0.f, 0.f}, b_go = (v2f){0.f, 0.f};
  if (act) {
    const float* wi = wih + l * 576;
    const float* wh = whh + l * 576;
#pragma unroll
    for (int k = 0; k < 12; ++k) {
      wx_if[k] = (v2f){ wi[(j     ) * 12 + k], wi[(j + 12) * 12 + k] };
      wx_go[k] = (v2f){ wi[(j + 24) * 12 + k], wi[(j + 36) * 12 + k] };
      wh_if[k] = (v2f){ wh[(j     ) * 12 + k], wh[(j + 12) * 12 + k] };
      wh_go[k] = (v2f){ wh[(j + 24) * 12 + k], wh[(j + 36) * 12 + k] };
    }
    const float* ba = bih + l * 48;
    const float* bb = bhh + l * 48;
    b_if = (v2f){ ba[j]      + bb[j],      ba[j + 12] + bb[j + 12] };
    b_go = (v2f){ ba[j + 24] + bb[j + 24], ba[j + 36] + bb[j + 36] };
  }

  // ---- feeder / tailer plumbing (hop payload = 384 floats: both chains) ----
  const int hop_in  = pr * 3 + seg - 1;                // valid if seg>0
  const int hop_out = pr * 3 + seg;                    // valid if seg<3
  const float* rin  = ring + (size_t)((seg > 0) ? hop_in : 0) * (RB * 384);
  float*       rout = ring + (size_t)((seg < 3) ? hop_out : 0) * (RB * 384);
  const bool is_feeder = (w == 0);
  const bool is_tailer = (w == 5) && (seg < 3);

  // cooperative 384-float copy: lane covers fk = lane + 64*k, k=0..5
  // batch layout (flat 384): [t(16)][chain(2)][j(12)]
  int s0o[6];   // seq0 gather offsets (per fk): tl*768 + ch*12 + jj  (+ runtime m,pair terms)
#pragma unroll
  for (int k = 0; k < 6; ++k) {
    const int fk = lane + 64 * k;
    const int tl = fk / 24, rem = fk - tl * 24;
    const int ch = rem / 12, jj = rem - ch * 12;
    s0o[k] = tl * 768 + ch * 12 + jj;
  }

  auto ld_batch = [&](int m, float* d) {
    if (seg == 0) {
      const float* b = seq0 + (size_t)m * 16 * 768 + pr * 24;
#pragma unroll
      for (int k = 0; k < 6; ++k) d[k] = b[s0o[k]];
    } else {
      const float* b = rin + (m & (RB - 1)) * 384;
#pragma unroll
      for (int k = 0; k < 6; ++k)
        d[k] = __hip_atomic_load(b + lane + 64 * k, __ATOMIC_RELAXED, __HIP_MEMORY_SCOPE_AGENT);
    }
  };

  float pend[6] = {0.f, 0.f, 0.f, 0.f, 0.f, 0.f};
  int kp = 0, kcons = 0;
  if (is_feeder) {
    if (seg > 0) kp = poll_ge_ag(&prog[hop_in], 2, 0);
    float cur[6];
    ld_batch(0, cur);
    ld_batch(1, pend);
#pragma unroll
    for (int k = 0; k < 6; ++k) xrf[lane + 64 * k] = cur[k];   // batch 0 -> buffer 0
  }

  float cstA = 0.f, cstB = 0.f;
  int pcache = 0, ccache = 0;

  // ---- one LSTM step for both chains; `guard` constant-folds per call site ----
  auto step = [&](int s, bool guard) __attribute__((always_inline)) {
    const int t  = s - pc;
    const int rb = (s & 1) ^ 1, wb = s & 1;

    const float *axA, *axB;
    if (p == 0) {
      if (w == 0) {
        float* base = xrf + ((s >> 4) & 1) * 384 + (s & 15) * 24;
        axA = base; axB = base + 12;
      } else {
        axA = &iring[w - 1][s & (IRS - 1)][0][0];
        axB = &iring[w - 1][s & (IRS - 1)][1][0];
      }
    } else {
      axA = &hloc[w][rb][0][(pc == 0 ? 0 : pc - 1) * 12];
      axB = &hloc[w][rb][1][(pc == 0 ? 0 : pc - 1) * 12];
    }
    const float* ahA = &hloc[w][rb][0][pc * 12];
    const float* ahB = &hloc[w][rb][1][pc * 12];

    float4 xA0 = ((const float4*)axA)[0], xA1 = ((const float4*)axA)[1], xA2 = ((const float4*)axA)[2];
    float4 hA0 = ((const float4*)ahA)[0], hA1 = ((const float4*)ahA)[1], hA2 = ((const float4*)ahA)[2];
    float4 xB0 = ((const float4*)axB)[0], xB1 = ((const float4*)axB)[1], xB2 = ((const float4*)axB)[2];
    float4 hB0 = ((const float4*)ahB)[0], hB1 = ((const float4*)ahB)[1], hB2 = ((const float4*)ahB)[2];
    float xvA[12] = {xA0.x,xA0.y,xA0.z,xA0.w, xA1.x,xA1.y,xA1.z,xA1.w, xA2.x,xA2.y,xA2.z,xA2.w};
    float hvA[12] = {hA0.x,hA0.y,hA0.z,hA0.w, hA1.x,hA1.y,hA1.z,hA1.w, hA2.x,hA2.y,hA2.z,hA2.w};
    float xvB[12] = {xB0.x,xB0.y,xB0.z,xB0.w, xB1.x,xB1.y,xB1.z,xB1.w, xB2.x,xB2.y,xB2.z,xB2.w};
    float hvB[12] = {hB0.x,hB0.y,hB0.z,hB0.w, hB1.x,hB1.y,hB1.z,hB1.w, hB2.x,hB2.y,hB2.z,hB2.w};

    // chain A gates
    v2f axifA = (v2f){0.f,0.f}, axgoA = (v2f){0.f,0.f};
    v2f ahifA = b_if, ahgoA = b_go;
    // chain B gates
    v2f axifB = (v2f){0.f,0.f}, axgoB = (v2f){0.f,0.f};
    v2f ahifB = b_if, ahgoB = b_go;
#pragma unroll
    for (int k = 0; k < 12; ++k) {
      v2f xxA = { xvA[k], xvA[k] }, hhA = { hvA[k], hvA[k] };
      v2f xxB = { xvB[k], xvB[k] }, hhB = { hvB[k], hvB[k] };
      axifA = __builtin_elementwise_fma(wx_if[k], xxA, axifA);
      axgoA = __builtin_elementwise_fma(wx_go[k], xxA, axgoA);
      ahifA = __builtin_elementwise_fma(wh_if[k], hhA, ahifA);
      ahgoA = __builtin_elementwise_fma(wh_go[k], hhA, ahgoA);
      axifB = __builtin_elementwise_fma(wx_if[k], xxB, axifB);
      axgoB = __builtin_elementwise_fma(wx_go[k], xxB, axgoB);
      ahifB = __builtin_elementwise_fma(wh_if[k], hhB, ahifB);
      ahgoB = __builtin_elementwise_fma(wh_go[k], hhB, ahgoB);
    }
    v2f aifA = axifA + ahifA, agoA = axgoA + ahgoA;
    v2f aifB = axifB + ahifB, agoB = axgoB + ahgoB;
    float igA = fast_sig(aifA.x), fgA = fast_sig(aifA.y);
    float ggA = fast_tanh(agoA.x), ogA = fast_sig(agoA.y);
    float igB = fast_sig(aifB.x), fgB = fast_sig(aifB.y);
    float ggB = fast_tanh(agoB.x), ogB = fast_sig(agoB.y);

    if (!guard) {
      cstA = fgA * cstA + igA * ggA;
      cstB = fgB * cstB + igB * ggB;
      float hnA = ogA * fast_tanh(cstA);
      float hnB = ogB * fast_tanh(cstB);
      hloc[w][wb][0][p * 12 + j] = hnA;
      hloc[w][wb][1][p * 12 + j] = hnB;
      if (p == 4) {
        if (w < 5) {
          iring[w][t & (IRS - 1)][0][j] = hnA;
          iring[w][t & (IRS - 1)][1][j] = hnB;
        } else if (seg < 3) {
          oring[t & 15][0][j] = hnA;
          oring[t & 15][1][j] = hnB;
        }
      }
    } else {
      const bool run = act && (t >= 0) && (t < TT);
      if (run) {
        cstA = fgA * cstA + igA * ggA;
        cstB = fgB * cstB + igB * ggB;
        float hnA = ogA * fast_tanh(cstA);
        float hnB = ogB * fast_tanh(cstB);
        hloc[w][wb][0][p * 12 + j] = hnA;
        hloc[w][wb][1][p * 12 + j] = hnB;
        if (p == 4) {
          if (w < 5) {
            iring[w][t & (IRS - 1)][0][j] = hnA;
            iring[w][t & (IRS - 1)][1][j] = hnB;
          } else if (seg < 3) {
            oring[t & 15][0][j] = hnA;
            oring[t & 15][1][j] = hnB;
          }
        }
        if (t == TT - 1) {
          hfin[l * 768 + (2 * pr)     * 12 + j] = hnA;
          hfin[l * 768 + (2 * pr + 1) * 12 + j] = hnB;
        }
      }
    }
  };

  for (int s4 = 0; s4 < 1024; s4 += 4) {
    // ---- batch boundary: feeder publishes batch m+1, starts loads for m+2 ----
    if (is_feeder && (s4 & 15) == 0) {
      const int m = s4 >> 4;
      if (m + 1 < NB) {
        float* xd = xrf + ((m + 1) & 1) * 384;
#pragma unroll
        for (int k = 0; k < 6; ++k) xd[lane + 64 * k] = pend[k];
      }
      if (m + 2 < NB) {
        if (seg > 0 && kp < m + 3) kp = poll_ge_ag(&prog[hop_in], m + 3, kp);
        ld_batch(m + 2, pend);     // stays in flight for the next 16 steps (no drains now)
      }
      if (seg > 0 && lane == 0)
        __hip_atomic_store(&cons[hop_in], m, __ATOMIC_RELAXED, __HIP_MEMORY_SCOPE_AGENT);
    }

    // ---- relaxed LDS flag checks, once per 4 steps ----
    if (w > 0 && s4 < TT) {
      const int tgt = (s4 + 4 < TT) ? (s4 + 4) : TT;
      if (pcache < tgt) {
        pcache = poll_ge_wg(&pflag[w - 1], tgt, pcache);
        asm volatile("" ::: "memory");
      }
    }
    if (w < 5 && s4 >= 36) {
      const int tgt = s4 - 32;
      if (ccache < tgt) {
        ccache = poll_ge_wg(&cflag[w + 1], tgt, ccache);
        asm volatile("" ::: "memory");
      }
    }

    if (s4 >= 4 && s4 < 1012) {
      step(s4 + 0, false); step(s4 + 1, false); step(s4 + 2, false); step(s4 + 3, false);
    } else {
      step(s4 + 0, true);  step(s4 + 1, true);  step(s4 + 2, true);  step(s4 + 3, true);
    }

    // ---- tailer: flush a completed 16-step batch (384 floats) to the L3 ring ----
    if (is_tailer) {
      if ((((s4 & 15) == 0) && s4 >= 16) || s4 == 1016) {
        const int m4 = (s4 - 1) >> 4;
        if (kcons < m4 - (RB - 1) + 1)
          kcons = poll_ge_ag(&cons[hop_out], m4 - RB + 1, kcons);
        const float* orf = &oring[0][0][0];
        float o[6];
#pragma unroll
        for (int k = 0; k < 6; ++k) o[k] = orf[lane + 64 * k];
        float* d = rout + (m4 & (RB - 1)) * 384;
#pragma unroll
        for (int k = 0; k < 6; ++k)
          __hip_atomic_store(d + lane + 64 * k, o[k], __ATOMIC_RELAXED, __HIP_MEMORY_SCOPE_AGENT);
        if (lane == 0)   // RELEASE: drains this wave's stores; other waves keep running
          __hip_atomic_store(&prog[hop_out], m4 + 1, __ATOMIC_RELEASE, __HIP_MEMORY_SCOPE_AGENT);
      }
    }

    // ---- relaxed flag posts (DS pipe in-order per wave orders data before flag) ----
    if (lane == 0) {
      asm volatile("" ::: "memory");
      if (w < 5)
        __hip_atomic_store(&pflag[w], s4, __ATOMIC_RELAXED, __HIP_MEMORY_SCOPE_WORKGROUP);
      if (w > 0 && s4 + 3 < TT)
        __hip_atomic_store(&cflag[w], s4 + 4, __ATOMIC_RELAXED, __HIP_MEMORY_SCOPE_WORKGROUP);
    }
  }

  // ---- epilogue: unblock any remaining pollers ----
  if (lane == 0) {
    asm volatile("" ::: "memory");
    if (w < 5) __hip_atomic_store(&pflag[w], BIGF, __ATOMIC_RELAXED, __HIP_MEMORY_SCOPE_WORKGROUP);
    if (w > 0) __hip_atomic_store(&cflag[w], BIGF, __ATOMIC_RELAXED, __HIP_MEMORY_SCOPE_WORKGROUP);
    if (is_feeder && seg > 0)
      __hip_atomic_store(&cons[hop_in], BIGF, __ATOMIC_RELAXED, __HIP_MEMORY_SCOPE_AGENT);
  }
}

// ---------------- head: lin1+relu, lin2+relu, mu, softplus(sigma) ----------------
__global__ void k_head(const float* __restrict__ hfin,
                       const float* __restrict__ w1, const float* __restrict__ b1,
                       const float* __restrict__ w2, const float* __restrict__ b2,
                       const float* __restrict__ wm, const float* __restrict__ bm,
                       const float* __restrict__ wsg, const float* __restrict__ bsg,
                       float* __restrict__ out)
{
  const int tid = threadIdx.x;
  __shared__ float s1[144], s2[144], sm[144], ss[144];
  __shared__ float v1[12], v2[12], vm[12], vs[12];
  if (tid < 144) { s1[tid] = w1[tid]; s2[tid] = w2[tid]; sm[tid] = wm[tid]; ss[tid] = wsg[tid]; }
  if (tid < 12)  { v1[tid] = b1[tid]; v2[tid] = b2[tid]; vm[tid] = bm[tid]; vs[tid] = bsg[tid]; }
  __syncthreads();
  const int r = blockIdx.x * 256 + tid;   // 0..7679 = b*120 + l
  const int b = r / 120, l = r - b * 120;
  float h[12];
#pragma unroll
  for (int k = 0; k < 12; ++k) h[k] = hfin[l * 768 + b * 12 + k];
  float u1[12];
#pragma unroll
  for (int u = 0; u < 12; ++u) {
    float a = v1[u];
#pragma unroll
    for (int k = 0; k < 12; ++k) a += s1[u * 12 + k] * h[k];
    u1[u] = fmaxf(a, 0.f);
  }
  float u2[12];
#pragma unroll
  for (int u = 0; u < 12; ++u) {
    float a = v2[u];
#pragma unroll
    for (int k = 0; k < 12; ++k) a += s2[u * 12 + k] * u1[k];
    u2[u] = fmaxf(a, 0.f);
  }
  const size_t base = (size_t)r * 12;
#pragma unroll
  for (int u = 0; u < 12; ++u) out[base + u] = u2[u];
#pragma unroll
  for (int u = 0; u < 12; ++u) {
    float a = vm[u];
#pragma unroll
    for (int k = 0; k < 12; ++k) a += sm[u * 12 + k] * u2[k];
    out[92160 + base + u] = a;
  }
#pragma unroll
  for (int u = 0; u < 12; ++u) {
    float a = vs[u];
#pragma unroll
    for (int k = 0; k < 12; ++k) a += ss[u * 12 + k] * u2[k];
    out[184320 + base + u] = fmaxf(a, 0.f) + log1pf(expf(-fabsf(a)));
  }
}

// ---------------- launcher ----------------
extern "C" void kernel_launch(void* const* d_in, const int* in_sizes, int n_in,
                              void* d_out, int out_size, void* d_ws, size_t ws_size,
                              hipStream_t stream)
{
  const float* x   = (const float*)d_in[0];
  const float* c1w = (const float*)d_in[1];
  const float* c1b = (const float*)d_in[2];
  const float* g1  = (const float*)d_in[3];
  const float* be1 = (const float*)d_in[4];
  const float* c2w = (const float*)d_in[5];
  const float* c2b = (const float*)d_in[6];
  const float* g2  = (const float*)d_in[7];
  const float* be2 = (const float*)d_in[8];
  const float* aw  = (const float*)d_in[9];
  const float* ab  = (const float*)d_in[10];
  const float* wih = (const float*)d_in[11];
  const float* whh = (const float*)d_in[12];
  const float* bih = (const float*)d_in[13];
  const float* bhh = (const float*)d_in[14];
  const float* l1w = (const float*)d_in[15];
  const float* l1b = (const float*)d_in[16];
  const float* l2w = (const float*)d_in[17];
  const float* l2b = (const float*)d_in[18];
  const float* muw = (const float*)d_in[19];
  const float* mub = (const float*)d_in[20];
  const float* sgw = (const float*)d_in[21];
  const float* sgb = (const float*)d_in[22];

  float* ws    = (float*)d_ws;
  float* stat1 = ws;                    // 12
  float* stat2 = ws + 12;               // 12
  float* aff1  = ws + 24;               // 12
  float* aff2  = ws + 36;               // 12
  int*   prog  = (int*)(ws + 64);       // 96 used
  int*   cons  = (int*)(ws + 304);      // 96 used
  float* y1    = ws + 576;              // 64*6*1020
  float* y2    = y1 + 391680;           // 64*6*1016
  float* seq0  = y2 + 390144;           // 1016*768
  float* ring  = seq0 + 780288;         // 96 hops * 8 batches * 384 floats (same size as before)
  float* hfin  = ring + (size_t)96 * RB * 384;    // 120*768

  hipMemsetAsync(d_ws, 0, 576 * sizeof(float), stream);  // zero stats + flags

  k_conv<<<384, 256, 0, stream>>>(x, c1w, c1b, nullptr, y1, stat1, 1024, 1020, 0);
  k_finalize<<<1, 64, 0, stream>>>(stat1, g1, be1, aff1, 1.f / 65280.f);
  k_conv<<<384, 256, 0, stream>>>(y1, c2w, c2b, aff1, y2, stat2, 1020, 1016, 1);
  k_finalize<<<1, 64, 0, stream>>>(stat2, g2, be2, aff2, 1.f / 65024.f);
  k_attn<<<1016, 768, 0, stream>>>(y2, aff2, aw, ab, seq0);
  k_lstm<<<128, TPB, 0, stream>>>(wih, whh, bih, bhh, seq0, ring, prog, cons, hfin);
  k_head<<<30, 256, 0, stream>>>(hfin, l1w, l1b, l2w, l2b, muw, mub, sgw, sgb, (float*)d_out);
}